// Round 8
// baseline (3407.550 us; speedup 1.0000x reference)
//
#include <hip/hip_runtime.h>
#include <math.h>

// ---------------- problem constants ----------------
#define B_    128
#define T_    64
#define INX   512
#define CTRL  512
#define NN    128
#define MMM   128
#define RR    4
#define LLh   134   // per-read-head instr length (3+MM+S)
#define NOUT  926
#define NTHR  512   // 2 batches/WG, 256 threads per batch-half

// Mem row stride 129: bank(129n+m)%32 = (n+m)%32 -> conflict-free both axes
#define MSTR  129

struct __align__(16) SM2 {
  float Mem[2][NN][MSTR];     // 132,096 B (persistent per-WG)
  float rw[2][RR][NN];        //   4,096 B
  float ww[2][NN];            //   1,024 B
  float instr[2][928];        //   7,424 B
  float rv[2][512];           //   4,096 B
  union {                     //   4,096 B (out_s dead by phase D)
    float out_s[2][512];
    struct { float red[2][256]; float invn[2][MMM]; } d;   // 3,072 B
  } u;
};  // 152,832 B -> 1 WG/CU, 64 WGs on 256 CUs (weights L2-resident per XCD)

// ---------------- 64-lane wave reductions (no barriers) ----------------
__device__ __forceinline__ float wsum64(float v) {
  #pragma unroll
  for (int m = 32; m >= 1; m >>= 1) v += __shfl_xor(v, m);
  return v;
}
__device__ __forceinline__ float wmax64(float v) {
  #pragma unroll
  for (int m = 32; m >= 1; m >>= 1) v = fmaxf(v, __shfl_xor(v, m));
  return v;
}

// ---------------- precompute: d_out = X(8192x512) @ Wc[0:512,:] + bc ----------------
__global__ __launch_bounds__(256) void pre_mm(const float* __restrict__ X,
                                              const float* __restrict__ Wc,
                                              const float* __restrict__ bc,
                                              float* __restrict__ out) {
  __shared__ float Xs[16][68];
  __shared__ float Ws[16][64];
  const int wg = blockIdx.x;
  const int r0 = (wg >> 3) * 64, c0 = (wg & 7) * 64;
  const int tid = threadIdx.x;
  const int ti = tid >> 4, tj = tid & 15;
  float acc[4][4] = {};
  for (int kk = 0; kk < 512; kk += 16) {
    __syncthreads();
    for (int e = tid; e < 1024; e += 256) {
      int i = e >> 4, k = e & 15;
      Xs[k][i] = X[(size_t)(r0 + i) * 512 + kk + k];
    }
    for (int e = tid; e < 1024; e += 256) {
      int k = e >> 6, j = e & 63;
      Ws[k][j] = Wc[(size_t)(kk + k) * CTRL + c0 + j];
    }
    __syncthreads();
    #pragma unroll
    for (int k = 0; k < 16; ++k) {
      float a0 = Xs[k][ti*4+0], a1 = Xs[k][ti*4+1], a2 = Xs[k][ti*4+2], a3 = Xs[k][ti*4+3];
      float b0 = Ws[k][tj*4+0], b1 = Ws[k][tj*4+1], b2 = Ws[k][tj*4+2], b3 = Ws[k][tj*4+3];
      acc[0][0]+=a0*b0; acc[0][1]+=a0*b1; acc[0][2]+=a0*b2; acc[0][3]+=a0*b3;
      acc[1][0]+=a1*b0; acc[1][1]+=a1*b1; acc[1][2]+=a1*b2; acc[1][3]+=a1*b3;
      acc[2][0]+=a2*b0; acc[2][1]+=a2*b1; acc[2][2]+=a2*b2; acc[2][3]+=a2*b3;
      acc[3][0]+=a3*b0; acc[3][1]+=a3*b1; acc[3][2]+=a3*b2; acc[3][3]+=a3*b3;
    }
  }
  #pragma unroll
  for (int i = 0; i < 4; ++i) {
    size_t o = (size_t)(r0 + ti*4 + i) * 512 + c0 + tj*4;
    float4 v = { acc[i][0] + bc[c0+tj*4+0], acc[i][1] + bc[c0+tj*4+1],
                 acc[i][2] + bc[c0+tj*4+2], acc[i][3] + bc[c0+tj*4+3] };
    *(float4*)&out[o] = v;
  }
}

// ---------------- one head task on one wave (64 lanes, no barriers, no LDS scratch) --
// tau in 0..9: batch = tau/5, head = tau%5. Reads pre-update Mem/invn/instr/w_old,
// writes rw[b][hd] (hd<4) or ww[b] (hd==4). The +-1 ring shift of wi is done with
// __shfl (register exchange) -- NO same-wave LDS write->read (that was UB, round 6).
__device__ __forceinline__ void do_head(SM2& sm, int tau, int lane) {
  const int b  = tau / 5;
  const int hd = tau - 5 * b;
  const int off = (hd < RR) ? hd * LLh : RR * LLh;
  const float* ins = sm.instr[b];
  const int n0 = lane, n1 = lane + 64;

  // key inv-norm over m
  float k0 = ins[off + n0], k1 = ins[off + n1];
  float invk = rsqrtf(fmaxf(wsum64(k0 * k0 + k1 * k1), 1e-12f));
  // scalar head params (wave-uniform LDS broadcasts)
  float beta = expf(ins[off + 128]);
  float gg = 1.f / (1.f + expf(-ins[off + 129]));
  float s0 = ins[off + 130], s1 = ins[off + 131], s2 = ins[off + 132];
  float smx = fmaxf(s0, fmaxf(s1, s2));
  float e0 = expf(s0 - smx), e1 = expf(s1 - smx), e2 = expf(s2 - smx);
  float esm = e0 + e1 + e2; s0 = e0 / esm; s1 = e1 / esm; s2 = e2 / esm;
  float spx = ins[off + 133];
  float tt = ((spx > 20.f) ? spx : log1pf(expf(spx))) + 1.0f;

  // sim[n] = (sum_m Mem[n][m]*invn[m]*k[m]) * invk * beta  (lane owns n0, n1)
  float p0 = 0.f, p1 = 0.f;
  #pragma unroll 4
  for (int m = 0; m < 128; ++m) {
    float km = sm.u.d.invn[b][m] * ins[off + m];
    p0 += sm.Mem[b][n0][m] * km;
    p1 += sm.Mem[b][n1][m] * km;
  }
  float sim0 = p0 * invk * beta, sim1 = p1 * invk * beta;
  float mx = wmax64(fmaxf(sim0, sim1));
  float ev0 = expf(sim0 - mx), ev1 = expf(sim1 - mx);
  float es = wsum64(ev0 + ev1);
  float wold0 = (hd < RR) ? sm.rw[b][hd][n0] : sm.ww[b][n0];
  float wold1 = (hd < RR) ? sm.rw[b][hd][n1] : sm.ww[b][n1];
  float wi0 = gg * (ev0 / es) + (1.f - gg) * wold0;   // wi[lane]
  float wi1 = gg * (ev1 / es) + (1.f - gg) * wold1;   // wi[lane+64]

  // ring shift wi[n-1], wi[n+1] mod 128 via register shuffles:
  int ls = (lane + 63) & 63;
  float A0 = __shfl(wi0, ls), A1 = __shfl(wi1, ls);
  float wprev0 = (lane == 0) ? A1 : A0;   // wi[(n0+127)&127]
  float wprev1 = (lane == 0) ? A0 : A1;   // wi[(n1+127)&127]
  int ln = (lane + 1) & 63;
  float B0 = __shfl(wi0, ln), B1 = __shfl(wi1, ln);
  float wnext0 = (lane == 63) ? B1 : B0;  // wi[(n0+1)&127]
  float wnext1 = (lane == 63) ? B0 : B1;  // wi[(n1+1)&127]

  float ws0 = s0 * wprev0 + s1 * wi0 + s2 * wnext0;
  float ws1 = s0 * wprev1 + s1 * wi1 + s2 * wnext1;
  float pv0 = powf(ws0, tt), pv1 = powf(ws1, tt);
  float inv = 1.f / (wsum64(pv0 + pv1) + 1e-12f);
  if (hd < RR) { sm.rw[b][hd][n0] = pv0 * inv; sm.rw[b][hd][n1] = pv1 * inv; }
  else         { sm.ww[b][n0]     = pv0 * inv; sm.ww[b][n1]     = pv1 * inv; }
}

// ---------------- persistent per-batch-pair kernel: NO grid sync ----------------
__global__ __launch_bounds__(512) void ntm2(const float* __restrict__ Wc,
                                            const float* __restrict__ Wk,
                                            const float* __restrict__ bk,
                                            float* __restrict__ out) {
  __shared__ SM2 sm;
  const int wg = blockIdx.x, tid = threadIdx.x;
  const int b0 = wg * 2;
  const int lt = tid & 255, bb = tid >> 8;   // half-local id / batch within WG
  const int j  = tid;                        // column id for GEMV phases
  const int wv = tid >> 6, lane = tid & 63;  // wave id / lane for phase D

  // ---- init state ----
  for (int e = tid; e < 2 * NN * MMM; e += NTHR) {
    int bl = e >> 14, n = (e >> 7) & 127;
    sm.Mem[bl][n][e & 127] = (n == NN / 2) ? 1.0f : 0.0f;
  }
  for (int e = tid; e < 2 * RR * NN; e += NTHR) ((float*)sm.rw)[e] = 0.0f;
  for (int e = tid; e < 2 * NN;      e += NTHR) ((float*)sm.ww)[e] = 0.0f;
  for (int e = tid; e < 2 * 512;     e += NTHR) ((float*)sm.rv)[e] = 0.0f;
  __syncthreads();

  for (int t = 0; t < T_; ++t) {
    // ===== phase B: out[b][t][j] = tanh(pre + rv_b @ Wc2[:,j]) =====
    // round-2 access pattern, unrolled 16-deep (16 scalar loads in flight)
    {
      float a0 = 0.f, a1 = 0.f;
      const float* wp = Wc + (size_t)INX * CTRL + j;
      for (int k16 = 0; k16 < 512; k16 += 16) {
        float w[16];
        #pragma unroll
        for (int i = 0; i < 16; ++i) w[i] = wp[(size_t)(k16 + i) * CTRL];
        float4 r0a = *(const float4*)&sm.rv[0][k16];
        float4 r0b = *(const float4*)&sm.rv[0][k16+4];
        float4 r0c = *(const float4*)&sm.rv[0][k16+8];
        float4 r0d = *(const float4*)&sm.rv[0][k16+12];
        float4 r1a = *(const float4*)&sm.rv[1][k16];
        float4 r1b = *(const float4*)&sm.rv[1][k16+4];
        float4 r1c = *(const float4*)&sm.rv[1][k16+8];
        float4 r1d = *(const float4*)&sm.rv[1][k16+12];
        a0 += r0a.x*w[0] + r0a.y*w[1] + r0a.z*w[2]  + r0a.w*w[3]
            + r0b.x*w[4] + r0b.y*w[5] + r0b.z*w[6]  + r0b.w*w[7]
            + r0c.x*w[8] + r0c.y*w[9] + r0c.z*w[10] + r0c.w*w[11]
            + r0d.x*w[12]+ r0d.y*w[13]+ r0d.z*w[14] + r0d.w*w[15];
        a1 += r1a.x*w[0] + r1a.y*w[1] + r1a.z*w[2]  + r1a.w*w[3]
            + r1b.x*w[4] + r1b.y*w[5] + r1b.z*w[6]  + r1b.w*w[7]
            + r1c.x*w[8] + r1c.y*w[9] + r1c.z*w[10] + r1c.w*w[11]
            + r1d.x*w[12]+ r1d.y*w[13]+ r1d.z*w[14] + r1d.w*w[15];
      }
      size_t o0 = ((size_t)(b0+0)*T_ + t)*CTRL + j;
      size_t o1 = ((size_t)(b0+1)*T_ + t)*CTRL + j;
      float v0 = tanhf(out[o0] + a0);
      float v1 = tanhf(out[o1] + a1);
      out[o0] = v0; out[o1] = v1;
      sm.u.out_s[0][j] = v0; sm.u.out_s[1][j] = v1;
    }
    __syncthreads();

    // ===== phase C: instr = out_t @ Wk + bk =====
    // thread j owns cols j and j+512 (if <926): 2 scalar streams, unroll-8
    // -> 16 loads in flight per iteration (same addresses/order as round 2)
    {
      const int c1 = (j < NOUT - 512) ? j + 512 : j;   // clamp to stay in-bounds
      float a00 = 0.f, a10 = 0.f, a01 = 0.f, a11 = 0.f;
      const float* wp0 = Wk + j;
      const float* wp1 = Wk + c1;
      for (int k8 = 0; k8 < 512; k8 += 8) {
        float w0[8], w1[8];
        #pragma unroll
        for (int i = 0; i < 8; ++i) w0[i] = wp0[(size_t)(k8 + i) * NOUT];
        #pragma unroll
        for (int i = 0; i < 8; ++i) w1[i] = wp1[(size_t)(k8 + i) * NOUT];
        float4 o0a = *(const float4*)&sm.u.out_s[0][k8];
        float4 o0b = *(const float4*)&sm.u.out_s[0][k8+4];
        float4 o1a = *(const float4*)&sm.u.out_s[1][k8];
        float4 o1b = *(const float4*)&sm.u.out_s[1][k8+4];
        a00 += o0a.x*w0[0] + o0a.y*w0[1] + o0a.z*w0[2] + o0a.w*w0[3]
             + o0b.x*w0[4] + o0b.y*w0[5] + o0b.z*w0[6] + o0b.w*w0[7];
        a01 += o0a.x*w1[0] + o0a.y*w1[1] + o0a.z*w1[2] + o0a.w*w1[3]
             + o0b.x*w1[4] + o0b.y*w1[5] + o0b.z*w1[6] + o0b.w*w1[7];
        a10 += o1a.x*w0[0] + o1a.y*w0[1] + o1a.z*w0[2] + o1a.w*w0[3]
             + o1b.x*w0[4] + o1b.y*w0[5] + o1b.z*w0[6] + o1b.w*w0[7];
        a11 += o1a.x*w1[0] + o1a.y*w1[1] + o1a.z*w1[2] + o1a.w*w1[3]
             + o1b.x*w1[4] + o1b.y*w1[5] + o1b.z*w1[6] + o1b.w*w1[7];
      }
      sm.instr[0][j] = a00 + bk[j];
      sm.instr[1][j] = a10 + bk[j];
      if (j < NOUT - 512) {
        sm.instr[0][j+512] = a01 + bk[j+512];
        sm.instr[1][j+512] = a11 + bk[j+512];
      }
    }
    __syncthreads();

    // ===== phase D: column norms -> 10 wave-parallel head tasks -> Mem -> rv =====
    {
      // 0) column inv-norms over n (reference: _l2n(Mem, axis=1))
      {
        int m = lt & 127, h = lt >> 7;
        float p = 0.f;
        #pragma unroll 8
        for (int q = 0; q < 64; ++q) { float v = sm.Mem[bb][h*64+q][m]; p += v*v; }
        sm.u.d.red[bb][lt] = p;
      }
      __syncthreads();
      if (lt < 128) sm.u.d.invn[bb][lt] =
          rsqrtf(fmaxf(sm.u.d.red[bb][lt] + sm.u.d.red[bb][lt+128], 1e-12f));
      __syncthreads();

      // 1) heads: pass 0 = tasks 0..7 (one per wave); pass 1 = tasks 8,9 (waves 0,1)
      do_head(sm, wv, lane);
      if (wv < 2) do_head(sm, 8 + wv, lane);
      __syncthreads();

      // 2) Mem = Mem*(1 - ww[n]*e[m]) + ww[n]*a[m]
      for (int e = lt; e < NN * MMM; e += 256) {
        int n = e >> 7, m = e & 127;
        float w = sm.ww[bb][n];
        sm.Mem[bb][n][m] = sm.Mem[bb][n][m] * (1.f - w * sm.instr[bb][670 + m])
                         + w * sm.instr[bb][798 + m];
      }
      __syncthreads();

      // 3) rv[r*128+m] = sum_n Mem[n][m] * rw[r][n]
      // thread owns column m for r = rbase and rbase+2: one Mem read feeds both
      {
        int m = lt & 127, rbase = lt >> 7;   // 0 or 1
        float acc0 = 0.f, acc1 = 0.f;
        const float* rw0 = sm.rw[bb][rbase];
        const float* rw2 = sm.rw[bb][rbase + 2];
        #pragma unroll 8
        for (int n = 0; n < NN; ++n) {
          float mv = sm.Mem[bb][n][m];
          acc0 += mv * rw0[n];
          acc1 += mv * rw2[n];
        }
        sm.rv[bb][rbase * 128 + m]       = acc0;
        sm.rv[bb][(rbase + 2) * 128 + m] = acc1;
      }
    }
    __syncthreads();   // rv ready for next step's phase B
  }
}

// ---------------- launch ----------------
extern "C" void kernel_launch(void* const* d_in, const int* in_sizes, int n_in,
                              void* d_out, int out_size, void* d_ws, size_t ws_size,
                              hipStream_t stream) {
  const float* x  = (const float*)d_in[0];
  const float* Wc = (const float*)d_in[1];
  const float* bc = (const float*)d_in[2];
  const float* Wk = (const float*)d_in[3];
  const float* bk = (const float*)d_in[4];
  float* out = (float*)d_out;

  pre_mm<<<dim3(1024), dim3(256), 0, stream>>>(x, Wc, bc, out);
  ntm2<<<dim3(B_ / 2), dim3(NTHR), 0, stream>>>(Wc, Wk, bk, out);
}

// Round 9
// 2879.527 us; speedup vs baseline: 1.1834x; 1.1834x over previous
//
#include <hip/hip_runtime.h>
#include <math.h>

// ---------------- problem constants ----------------
#define B_    128
#define T_    64
#define INX   512
#define CTRL  512
#define NN    128
#define MMM   128
#define RR    4
#define LLh   134   // per-read-head instr length (3+MM+S)
#define NOUT  926
#define NTHR  1024  // 2 batches/WG, 16 waves/CU: (col j = tid&511, k-half = tid>>9)

// Mem row stride 129: bank(129n+m)%32 = (n+m)%32 -> conflict-free both axes
#define MSTR  129

struct __align__(16) SM2 {
  float Mem[2][NN][MSTR];     // 132,096 B (persistent per-WG)
  float rw[2][RR][NN];        //   4,096 B
  float ww[2][NN];            //   1,024 B
  float instr[2][928];        //   7,424 B
  float rv[2][512];           //   4,096 B
  union {                     //  12,288 B
    struct { float out_s[2][512]; float red[512][4]; } c;  // GEMV phases (out_s+red coexist)
    struct { float red[2][512]; float invn[2][MMM]; } d;   // phase-D norms (out_s dead)
  } u;
};  // 161,024 B <= 163,840 -> 1 WG/CU, 64 WGs, 16 waves/CU

// ---------------- 64-lane wave reductions (no barriers) ----------------
__device__ __forceinline__ float wsum64(float v) {
  #pragma unroll
  for (int m = 32; m >= 1; m >>= 1) v += __shfl_xor(v, m);
  return v;
}
__device__ __forceinline__ float wmax64(float v) {
  #pragma unroll
  for (int m = 32; m >= 1; m >>= 1) v = fmaxf(v, __shfl_xor(v, m));
  return v;
}

// ---------------- precompute: d_out = X(8192x512) @ Wc[0:512,:] + bc ----------------
__global__ __launch_bounds__(256) void pre_mm(const float* __restrict__ X,
                                              const float* __restrict__ Wc,
                                              const float* __restrict__ bc,
                                              float* __restrict__ out) {
  __shared__ float Xs[16][68];
  __shared__ float Ws[16][64];
  const int wg = blockIdx.x;
  const int r0 = (wg >> 3) * 64, c0 = (wg & 7) * 64;
  const int tid = threadIdx.x;
  const int ti = tid >> 4, tj = tid & 15;
  float acc[4][4] = {};
  for (int kk = 0; kk < 512; kk += 16) {
    __syncthreads();
    for (int e = tid; e < 1024; e += 256) {
      int i = e >> 4, k = e & 15;
      Xs[k][i] = X[(size_t)(r0 + i) * 512 + kk + k];
    }
    for (int e = tid; e < 1024; e += 256) {
      int k = e >> 6, jx = e & 63;
      Ws[k][jx] = Wc[(size_t)(kk + k) * CTRL + c0 + jx];
    }
    __syncthreads();
    #pragma unroll
    for (int k = 0; k < 16; ++k) {
      float a0 = Xs[k][ti*4+0], a1 = Xs[k][ti*4+1], a2 = Xs[k][ti*4+2], a3 = Xs[k][ti*4+3];
      float b0 = Ws[k][tj*4+0], b1 = Ws[k][tj*4+1], b2 = Ws[k][tj*4+2], b3 = Ws[k][tj*4+3];
      acc[0][0]+=a0*b0; acc[0][1]+=a0*b1; acc[0][2]+=a0*b2; acc[0][3]+=a0*b3;
      acc[1][0]+=a1*b0; acc[1][1]+=a1*b1; acc[1][2]+=a1*b2; acc[1][3]+=a1*b3;
      acc[2][0]+=a2*b0; acc[2][1]+=a2*b1; acc[2][2]+=a2*b2; acc[2][3]+=a2*b3;
      acc[3][0]+=a3*b0; acc[3][1]+=a3*b1; acc[3][2]+=a3*b2; acc[3][3]+=a3*b3;
    }
  }
  #pragma unroll
  for (int i = 0; i < 4; ++i) {
    size_t o = (size_t)(r0 + ti*4 + i) * 512 + c0 + tj*4;
    float4 v = { acc[i][0] + bc[c0+tj*4+0], acc[i][1] + bc[c0+tj*4+1],
                 acc[i][2] + bc[c0+tj*4+2], acc[i][3] + bc[c0+tj*4+3] };
    *(float4*)&out[o] = v;
  }
}

// ---------------- one head task on one wave (64 lanes, no barriers, no LDS scratch) --
// tau in 0..9: batch = tau/5, head = tau%5. Ring shift of wi via __shfl (round-7 proven).
__device__ __forceinline__ void do_head(SM2& sm, int tau, int lane) {
  const int b  = tau / 5;
  const int hd = tau - 5 * b;
  const int off = (hd < RR) ? hd * LLh : RR * LLh;
  const float* ins = sm.instr[b];
  const int n0 = lane, n1 = lane + 64;

  float k0 = ins[off + n0], k1 = ins[off + n1];
  float invk = rsqrtf(fmaxf(wsum64(k0 * k0 + k1 * k1), 1e-12f));
  float beta = expf(ins[off + 128]);
  float gg = 1.f / (1.f + expf(-ins[off + 129]));
  float s0 = ins[off + 130], s1 = ins[off + 131], s2 = ins[off + 132];
  float smx = fmaxf(s0, fmaxf(s1, s2));
  float e0 = expf(s0 - smx), e1 = expf(s1 - smx), e2 = expf(s2 - smx);
  float esm = e0 + e1 + e2; s0 = e0 / esm; s1 = e1 / esm; s2 = e2 / esm;
  float spx = ins[off + 133];
  float tt = ((spx > 20.f) ? spx : log1pf(expf(spx))) + 1.0f;

  float p0 = 0.f, p1 = 0.f;
  #pragma unroll 4
  for (int m = 0; m < 128; ++m) {
    float km = sm.u.d.invn[b][m] * ins[off + m];
    p0 += sm.Mem[b][n0][m] * km;
    p1 += sm.Mem[b][n1][m] * km;
  }
  float sim0 = p0 * invk * beta, sim1 = p1 * invk * beta;
  float mx = wmax64(fmaxf(sim0, sim1));
  float ev0 = expf(sim0 - mx), ev1 = expf(sim1 - mx);
  float es = wsum64(ev0 + ev1);
  float wold0 = (hd < RR) ? sm.rw[b][hd][n0] : sm.ww[b][n0];
  float wold1 = (hd < RR) ? sm.rw[b][hd][n1] : sm.ww[b][n1];
  float wi0 = gg * (ev0 / es) + (1.f - gg) * wold0;
  float wi1 = gg * (ev1 / es) + (1.f - gg) * wold1;

  int ls = (lane + 63) & 63;
  float A0 = __shfl(wi0, ls), A1 = __shfl(wi1, ls);
  float wprev0 = (lane == 0) ? A1 : A0;
  float wprev1 = (lane == 0) ? A0 : A1;
  int ln = (lane + 1) & 63;
  float B0 = __shfl(wi0, ln), B1 = __shfl(wi1, ln);
  float wnext0 = (lane == 63) ? B1 : B0;
  float wnext1 = (lane == 63) ? B0 : B1;

  float ws0 = s0 * wprev0 + s1 * wi0 + s2 * wnext0;
  float ws1 = s0 * wprev1 + s1 * wi1 + s2 * wnext1;
  float pv0 = powf(ws0, tt), pv1 = powf(ws1, tt);
  float inv = 1.f / (wsum64(pv0 + pv1) + 1e-12f);
  if (hd < RR) { sm.rw[b][hd][n0] = pv0 * inv; sm.rw[b][hd][n1] = pv1 * inv; }
  else         { sm.ww[b][n0]     = pv0 * inv; sm.ww[b][n1]     = pv1 * inv; }
}

// ---------------- persistent per-batch-pair kernel: NO grid sync ----------------
__global__ __launch_bounds__(1024) void ntm2(const float* __restrict__ Wc,
                                             const float* __restrict__ Wk,
                                             const float* __restrict__ bk,
                                             float* __restrict__ out) {
  __shared__ SM2 sm;
  const int wg = blockIdx.x, tid = threadIdx.x;
  const int b0 = wg * 2;
  const int j  = tid & 511;                  // column id for GEMV phases
  const int kh = tid >> 9;                   // k-half 0/1 (also batch id in phase D)
  const int lt = tid & 511, bb = tid >> 9;   // phase-D aliases
  const int wv = tid >> 6, lane = tid & 63;  // wave id / lane

  // ---- init state ----
  for (int e = tid; e < 2 * NN * MMM; e += NTHR) {
    int bl = e >> 14, n = (e >> 7) & 127;
    sm.Mem[bl][n][e & 127] = (n == NN / 2) ? 1.0f : 0.0f;
  }
  for (int e = tid; e < 2 * RR * NN; e += NTHR) ((float*)sm.rw)[e] = 0.0f;
  for (int e = tid; e < 2 * NN;      e += NTHR) ((float*)sm.ww)[e] = 0.0f;
  for (int e = tid; e < 2 * 512;     e += NTHR) ((float*)sm.rv)[e] = 0.0f;
  __syncthreads();

  for (int t = 0; t < T_; ++t) {
    // ===== phase B: out[b][t][j] = tanh(pre + rv_b @ Wc2[:,j]) =====
    // thread (j, kh): k-half of column j for BOTH batches; round-7 8-deep body
    {
      const int kb = kh * 256;
      float a0 = 0.f, a1 = 0.f;
      const float* wp = Wc + (size_t)(INX + kb) * CTRL + j;
      for (int k8 = 0; k8 < 256; k8 += 8) {
        float w0 = wp[(size_t)(k8+0)*CTRL];
        float w1 = wp[(size_t)(k8+1)*CTRL];
        float w2 = wp[(size_t)(k8+2)*CTRL];
        float w3 = wp[(size_t)(k8+3)*CTRL];
        float w4 = wp[(size_t)(k8+4)*CTRL];
        float w5 = wp[(size_t)(k8+5)*CTRL];
        float w6 = wp[(size_t)(k8+6)*CTRL];
        float w7 = wp[(size_t)(k8+7)*CTRL];
        float4 r0a = *(const float4*)&sm.rv[0][kb+k8];
        float4 r0b = *(const float4*)&sm.rv[0][kb+k8+4];
        float4 r1a = *(const float4*)&sm.rv[1][kb+k8];
        float4 r1b = *(const float4*)&sm.rv[1][kb+k8+4];
        a0 += r0a.x*w0 + r0a.y*w1 + r0a.z*w2 + r0a.w*w3
            + r0b.x*w4 + r0b.y*w5 + r0b.z*w6 + r0b.w*w7;
        a1 += r1a.x*w0 + r1a.y*w1 + r1a.z*w2 + r1a.w*w3
            + r1b.x*w4 + r1b.y*w5 + r1b.z*w6 + r1b.w*w7;
      }
      if (kh == 1) { sm.u.c.red[j][0] = a0; sm.u.c.red[j][1] = a1; }
      __syncthreads();
      if (kh == 0) {
        a0 += sm.u.c.red[j][0];
        a1 += sm.u.c.red[j][1];
        size_t o0 = ((size_t)(b0+0)*T_ + t)*CTRL + j;
        size_t o1 = ((size_t)(b0+1)*T_ + t)*CTRL + j;
        float v0 = tanhf(out[o0] + a0);
        float v1 = tanhf(out[o1] + a1);
        out[o0] = v0; out[o1] = v1;
        sm.u.c.out_s[0][j] = v0; sm.u.c.out_s[1][j] = v1;
      }
    }
    __syncthreads();

    // ===== phase C: instr = out_t @ Wk + bk =====
    // thread (j, kh): k-half of cols j and j+512 (if <926); round-7 4+4 body
    {
      const int kb = kh * 256;
      const int c1 = (j < NOUT - 512) ? j + 512 : j;   // clamp to stay in-bounds
      float a00 = 0.f, a10 = 0.f, a01 = 0.f, a11 = 0.f;
      const float* wp0 = Wk + (size_t)kb * NOUT + j;
      const float* wp1 = Wk + (size_t)kb * NOUT + c1;
      for (int k4 = 0; k4 < 256; k4 += 4) {
        float4 o0 = *(const float4*)&sm.u.c.out_s[0][kb + k4];
        float4 o1 = *(const float4*)&sm.u.c.out_s[1][kb + k4];
        #pragma unroll
        for (int i = 0; i < 4; ++i) {
          float w0 = wp0[(size_t)(k4+i)*NOUT];
          float w1 = wp1[(size_t)(k4+i)*NOUT];
          float e0 = (i==0)? o0.x : (i==1)? o0.y : (i==2)? o0.z : o0.w;
          float e1 = (i==0)? o1.x : (i==1)? o1.y : (i==2)? o1.z : o1.w;
          a00 += e0 * w0; a01 += e0 * w1;
          a10 += e1 * w0; a11 += e1 * w1;
        }
      }
      if (kh == 1) {
        float4 v = { a00, a01, a10, a11 };
        *(float4*)&sm.u.c.red[j][0] = v;
      }
      __syncthreads();
      if (kh == 0) {
        float4 q = *(const float4*)&sm.u.c.red[j][0];
        a00 += q.x; a01 += q.y; a10 += q.z; a11 += q.w;
        sm.instr[0][j] = a00 + bk[j];
        sm.instr[1][j] = a10 + bk[j];
        if (j < NOUT - 512) {
          sm.instr[0][j+512] = a01 + bk[j+512];
          sm.instr[1][j+512] = a11 + bk[j+512];
        }
      }
    }
    __syncthreads();

    // ===== phase D: column norms -> 10 wave-parallel head tasks -> Mem -> rv =====
    {
      // 0) column inv-norms over n: 4-way split per batch (1024 threads)
      {
        int m = lt & 127, h = lt >> 7;   // h 0..3
        float p = 0.f;
        #pragma unroll 8
        for (int q = 0; q < 32; ++q) { float v = sm.Mem[bb][h*32+q][m]; p += v*v; }
        sm.u.d.red[bb][lt] = p;
      }
      __syncthreads();
      if (lt < 128) sm.u.d.invn[bb][lt] =
          rsqrtf(fmaxf(sm.u.d.red[bb][lt] + sm.u.d.red[bb][lt+128]
                     + sm.u.d.red[bb][lt+256] + sm.u.d.red[bb][lt+384], 1e-12f));
      __syncthreads();

      // 1) heads: 10 tasks on waves 0..9, ONE pass
      if (wv < 10) do_head(sm, wv, lane);
      __syncthreads();

      // 2) Mem = Mem*(1 - ww[n]*e[m]) + ww[n]*a[m]
      for (int e = tid; e < 2 * NN * MMM; e += NTHR) {
        int bl = e >> 14, n = (e >> 7) & 127, m = e & 127;
        float w = sm.ww[bl][n];
        sm.Mem[bl][n][m] = sm.Mem[bl][n][m] * (1.f - w * sm.instr[bl][670 + m])
                         + w * sm.instr[bl][798 + m];
      }
      __syncthreads();

      // 3) rv: exactly one output per thread (2 batches x 4 r x 128 m = 1024)
      {
        int m = tid & 127, r = (tid >> 7) & 3, bl = tid >> 9;
        float acc = 0.f;
        const float* rwr = sm.rw[bl][r];
        #pragma unroll 8
        for (int n = 0; n < NN; ++n) acc += sm.Mem[bl][n][m] * rwr[n];
        sm.rv[bl][r * 128 + m] = acc;
      }
    }
    __syncthreads();   // rv ready for next step's phase B
  }
}

// ---------------- launch ----------------
extern "C" void kernel_launch(void* const* d_in, const int* in_sizes, int n_in,
                              void* d_out, int out_size, void* d_ws, size_t ws_size,
                              hipStream_t stream) {
  const float* x  = (const float*)d_in[0];
  const float* Wc = (const float*)d_in[1];
  const float* bc = (const float*)d_in[2];
  const float* Wk = (const float*)d_in[3];
  const float* bk = (const float*)d_in[4];
  float* out = (float*)d_out;

  pre_mm<<<dim3(1024), dim3(256), 0, stream>>>(x, Wc, bc, out);
  ntm2<<<dim3(B_ / 2), dim3(NTHR), 0, stream>>>(Wc, Wk, bk, out);
}